// Round 11
// baseline (363.986 us; speedup 1.0000x reference)
//
#include <hip/hip_runtime.h>
#include <hip/hip_bf16.h>

typedef unsigned short u16;
typedef unsigned int   u32;
typedef __attribute__((ext_vector_type(8))) short bf16x8;
typedef __attribute__((ext_vector_type(4))) float f32x4;

static constexpr int kS = 128, kD = 1024, kC = 65536, kN = 512, kNNZ = 262144;

__device__ __forceinline__ u16 f2bf(float x) {
  u32 u = __float_as_uint(x);
  u32 r = (u + 0x7fffu + ((u >> 16) & 1u)) >> 16;   // RTNE
  return (u16)r;
}
__device__ __forceinline__ u32 pack2(float a, float b) {
  return (u32)f2bf(a) | ((u32)f2bf(b) << 16);
}
// HW packed convert: v_cvt_pk_bf16_f32 (RTNE), a -> low16, b -> high16
__device__ __forceinline__ u32 pk(float a, float b) {
  __hip_bfloat162 h = __float22bfloat162_rn(float2{a, b});
  union { __hip_bfloat162 v; u32 u; } c; c.v = h;
  return c.u;
}
__device__ __forceinline__ float bf_lo(u32 v) { return __uint_as_float(v << 16); }
__device__ __forceinline__ float bf_hi(u32 v) { return __uint_as_float(v & 0xffff0000u); }

__device__ __forceinline__ void gload16(const void* g, void* l) {
  __builtin_amdgcn_global_load_lds(
      (const __attribute__((address_space(1))) void*)g,
      (__attribute__((address_space(3))) void*)l, 16, 0, 0);
}

// ---------------- BN stats: two-stage partial sums ----------------
__global__ void k_bn_part(const float* __restrict__ enc, const int* __restrict__ bidx,
                          const int* __restrict__ tgt, float* __restrict__ part) {
  __shared__ int offs[64];
  int n0 = blockIdx.y * 64;
  if (threadIdx.x < 64) offs[threadIdx.x] = bidx[n0 + threadIdx.x] * kS + tgt[n0 + threadIdx.x];
  __syncthreads();
  int d = blockIdx.x * 256 + threadIdx.x;
  float s = 0.f, ss = 0.f;
  for (int i = 0; i < 64; ++i) {
    float v = enc[(size_t)offs[i] * kD + d];
    s += v; ss += v * v;
  }
  part[(blockIdx.y * 2 + 0) * kD + d] = s;
  part[(blockIdx.y * 2 + 1) * kD + d] = ss;
}

__global__ void k_bn_fin(const float* __restrict__ part, float* __restrict__ mean,
                         float* __restrict__ rstd) {
  int d = blockIdx.x * 256 + threadIdx.x;
  float s = 0.f, ss = 0.f;
#pragma unroll
  for (int b = 0; b < 8; ++b) {
    s  += part[(b * 2 + 0) * kD + d];
    ss += part[(b * 2 + 1) * kD + d];
  }
  float m = s * (1.f / kN);
  float var = ss * (1.f / kN) - m * m;
  mean[d] = m;
  rstd[d] = 1.f / sqrtf(var + 1e-5f);
}

// ---------------- BN apply + pack into fragment-major Bp ----------------
// Bp entry (g, n) at flat g*512+n, 8 bf16 = h0[n][g*8 .. g*8+8]
__global__ void k_bn_pack(const float* __restrict__ enc, const int* __restrict__ bidx,
                          const int* __restrict__ tgt, const float* __restrict__ mean,
                          const float* __restrict__ rstd, u16* __restrict__ Bp) {
  int i = blockIdx.x * 256 + threadIdx.x;     // 256 blocks x 256 = 65536 entries
  int n = i & 511;
  int g = i >> 9;
  int k0 = g * 8;
  size_t src = (size_t)(bidx[n] * kS + tgt[n]) * kD + k0;
  float4 v0 = *(const float4*)(enc + src);
  float4 v1 = *(const float4*)(enc + src + 4);
  float4 m0 = *(const float4*)(mean + k0);
  float4 m1 = *(const float4*)(mean + k0 + 4);
  float4 r0 = *(const float4*)(rstd + k0);
  float4 r1 = *(const float4*)(rstd + k0 + 4);
  u32 q0 = pack2((v0.x - m0.x) * r0.x, (v0.y - m0.y) * r0.y);
  u32 q1 = pack2((v0.z - m0.z) * r0.z, (v0.w - m0.w) * r0.w);
  u32 q2 = pack2((v1.x - m1.x) * r1.x, (v1.y - m1.y) * r1.y);
  u32 q3 = pack2((v1.z - m1.z) * r1.z, (v1.w - m1.w) * r1.w);
  *(uint4*)(Bp + (size_t)i * 8) = make_uint4(q0, q1, q2, q3);
}

// ---------------- sort: histogram / scan / scatter ----------------
__global__ void k_hist(const int* __restrict__ rows, int* __restrict__ hist) {
  int e = blockIdx.x * blockDim.x + threadIdx.x;
  if (e < kNNZ) atomicAdd(&hist[rows[e]], 1);
}

__global__ __launch_bounds__(1024) void k_scan(int* __restrict__ hist, int* __restrict__ cursor) {
  __shared__ int sm[1024];
  int t = threadIdx.x;
  int base = t * 64;
  int sum = 0;
  for (int i = 0; i < 64; ++i) sum += hist[base + i];
  sm[t] = sum;
  __syncthreads();
  for (int off = 1; off < 1024; off <<= 1) {
    int v = (t >= off) ? sm[t - off] : 0;
    __syncthreads();
    sm[t] += v;
    __syncthreads();
  }
  int run = sm[t] - sum;
  for (int i = 0; i < 64; ++i) {
    int v = hist[base + i];
    hist[base + i] = run;
    cursor[base + i] = run;
    run += v;
  }
  if (t == 1023) hist[kC] = run;
}

__global__ void k_scatter(const int* __restrict__ rows, const int* __restrict__ cols,
                          const float* __restrict__ vals, int* __restrict__ cursor,
                          int* __restrict__ scol, float* __restrict__ sval) {
  int e = blockIdx.x * blockDim.x + threadIdx.x;
  if (e < kNNZ) {
    int r = rows[e];
    int p = atomicAdd(&cursor[r], 1);
    scol[p] = cols[e];
    sval[p] = vals[e];
  }
}

// ---------------- fused GEMM v6: 256-thr blocks, 4 barrier domains/CU ----------------
// BM=64 x BN=256, BK=64, 4 waves (1M x 4N), acc[4][4], 4 blocks/CU (regs<=128).
// A: f32 via global_load_lds DMA (zero staging VALU) into [64][64] f32 dbuf tile;
//    16B slots XOR'd by row&15 on BOTH DMA-source and read (rule 21) -> 2-way free.
//    f32->bf16 at fragment read via HW v_cvt_pk_bf16_f32 (4 ops/frag).
// B: direct L2->reg from fragment-major Bp. One __syncthreads per K-step.
// Grid (2, 1024): n-split fastest so the 2nd W pass hits L2/L3 hot.
__global__ __launch_bounds__(256, 4)
void k_gemm_f6(const float* __restrict__ W, const u16* __restrict__ Bp,
               const float* __restrict__ bias, u16* __restrict__ h1t) {
  __shared__ __align__(16) float Ab[2][64 * 64];   // 2 x 16 KB
  const int t = threadIdx.x;
  const int l = t & 63, w = t >> 6;                // 4 waves
  const int wn = w * 64;
  const int cb = blockIdx.y * 64;
  const int nb0 = blockIdx.x * 256;
  const int q = l >> 4, ln = l & 15;

  // DMA: 1024 16B slots; thread covers s = t + k*256.
  // slot s holds row r=s>>4, f32-chunk c=(s&15)^(r&15) -> pre-swizzled source.
  const float* gs0; const float* gs1; const float* gs2; const float* gs3;
  {
    int s0 = t, s1 = t + 256, s2 = t + 512, s3 = t + 768;
    gs0 = W + (size_t)(cb + (s0 >> 4)) * kD + ((s0 & 15) ^ ((s0 >> 4) & 15)) * 4;
    gs1 = W + (size_t)(cb + (s1 >> 4)) * kD + ((s1 & 15) ^ ((s1 >> 4) & 15)) * 4;
    gs2 = W + (size_t)(cb + (s2 >> 4)) * kD + ((s2 & 15) ^ ((s2 >> 4) & 15)) * 4;
    gs3 = W + (size_t)(cb + (s3 >> 4)) * kD + ((s3 & 15) ^ ((s3 >> 4) & 15)) * 4;
  }

  // B fragment base: frag (g, n) at Bp[(g*512+n)*8]; g = tt*8 + ks*4 + q
  const u16* gB = Bp + ((size_t)q * 512 + nb0 + wn + ln) * 8;

  f32x4 acc[4][4];
#pragma unroll
  for (int a = 0; a < 4; ++a)
#pragma unroll
    for (int b = 0; b < 4; ++b) acc[a][b] = (f32x4){0.f, 0.f, 0.f, 0.f};

  // prologue: DMA tile 0 into Ab[0]
  gload16(gs0, (char*)Ab[0] + (t + 0) * 16);
  gload16(gs1, (char*)Ab[0] + (t + 256) * 16);
  gload16(gs2, (char*)Ab[0] + (t + 512) * 16);
  gload16(gs3, (char*)Ab[0] + (t + 768) * 16);
  __syncthreads();

#pragma unroll 2
  for (int tt = 0; tt < 16; ++tt) {
    const int cur = tt & 1;
    if (tt < 15) {                       // DMA next K-tile, in flight across compute
      int go = (tt + 1) * 64;
      char* nb_ = (char*)Ab[cur ^ 1];
      gload16(gs0 + go, nb_ + (t + 0) * 16);
      gload16(gs1 + go, nb_ + (t + 256) * 16);
      gload16(gs2 + go, nb_ + (t + 512) * 16);
      gload16(gs3 + go, nb_ + (t + 768) * 16);
    }
    const float* curb = Ab[cur];
#pragma unroll
    for (int ks = 0; ks < 2; ++ks) {
      bf16x8 bv[4];
#pragma unroll
      for (int nb = 0; nb < 4; ++nb)
        bv[nb] = *(const bf16x8*)(gB + (size_t)(tt * 8 + ks * 4) * 4096 + nb * 128);
#pragma unroll
      for (int mb = 0; mb < 4; ++mb) {
        int rr = mb * 16 + ln;
        int sb = ks * 8 + q * 2;
        const float4* rowp = (const float4*)(curb + rr * 64);
        float4 a0 = rowp[(sb + 0) ^ (rr & 15)];
        float4 a1 = rowp[(sb + 1) ^ (rr & 15)];
        union { u32 u[4]; bf16x8 v; } cv;
        cv.u[0] = pk(a0.x, a0.y); cv.u[1] = pk(a0.z, a0.w);
        cv.u[2] = pk(a1.x, a1.y); cv.u[3] = pk(a1.z, a1.w);
#pragma unroll
        for (int nb = 0; nb < 4; ++nb)
          acc[mb][nb] = __builtin_amdgcn_mfma_f32_16x16x32_bf16(cv.v, bv[nb], acc[mb][nb], 0, 0, 0);
      }
    }
    __syncthreads();   // reads of cur done + next-tile DMA drained
  }

  // epilogue: + bias, swish, bf16 store (C/D map: col=lane&15, row=(lane>>4)*4+i)
#pragma unroll
  for (int mb = 0; mb < 4; ++mb) {
    int rb = mb * 16 + q * 4;
#pragma unroll
    for (int i = 0; i < 4; ++i) {
      int c = cb + rb + i;
      float bvs = bias[c];
#pragma unroll
      for (int nb = 0; nb < 4; ++nb) {
        float x = acc[mb][nb][i] + bvs;
        float sw = x / (1.f + __expf(-x));
        h1t[(size_t)c * kN + (nb0 + wn + nb * 16 + ln)] = f2bf(sw);
      }
    }
  }
}

// ---------------- spmm: 32 rows/block, 2-deep edge pipeline, transposed write ----------------
#define FMA8(cv, v)                                                        \
  a0 = fmaf(v, bf_lo(cv.x), a0); a1 = fmaf(v, bf_hi(cv.x), a1);            \
  a2 = fmaf(v, bf_lo(cv.y), a2); a3 = fmaf(v, bf_hi(cv.y), a3);            \
  a4 = fmaf(v, bf_lo(cv.z), a4); a5 = fmaf(v, bf_hi(cv.z), a5);            \
  a6 = fmaf(v, bf_lo(cv.w), a6); a7 = fmaf(v, bf_hi(cv.w), a7);

__global__ __launch_bounds__(512)
void k_spmm(const u16* __restrict__ h1t, const int* __restrict__ rowptr,
            const int* __restrict__ scol, const float* __restrict__ sval,
            float* __restrict__ out) {
  __shared__ float tile[32 * 512];   // XOR-swizzled, 64 KB
  int r0 = blockIdx.x * 32;
  int t = threadIdx.x, w = t >> 6, l = t & 63;
#pragma unroll
  for (int j = 0; j < 4; ++j) {
    int rl = w * 4 + j;
    int r = r0 + rl;
    uint4 hv = ((const uint4*)(h1t + (size_t)r * kN))[l];
    float a0 = bf_lo(hv.x), a1 = bf_hi(hv.x), a2 = bf_lo(hv.y), a3 = bf_hi(hv.y);
    float a4 = bf_lo(hv.z), a5 = bf_hi(hv.z), a6 = bf_lo(hv.w), a7 = bf_hi(hv.w);
    int e0 = rowptr[r], e1 = rowptr[r + 1];
    uint4 cv0 = {}, cv1 = {};
    float v0 = 0.f, v1 = 0.f;
    if (e0 < e1) {                    // 2-deep pipeline: two independent gather regs
      v0 = sval[e0];
      cv0 = ((const uint4*)(h1t + (size_t)scol[e0] * kN))[l];
    }
    if (e0 + 1 < e1) {
      v1 = sval[e0 + 1];
      cv1 = ((const uint4*)(h1t + (size_t)scol[e0 + 1] * kN))[l];
    }
    for (int e = e0; e < e1; e += 2) {
      FMA8(cv0, v0);
      if (e + 2 < e1) {
        v0 = sval[e + 2];
        cv0 = ((const uint4*)(h1t + (size_t)scol[e + 2] * kN))[l];
      }
      if (e + 1 < e1) {
        FMA8(cv1, v1);
        if (e + 3 < e1) {
          v1 = sval[e + 3];
          cv1 = ((const uint4*)(h1t + (size_t)scol[e + 3] * kN))[l];
        }
      }
    }
    int sw = (rl & 7) << 2;          // XOR bits 2..4 keep float4 groups intact
    *(float4*)&tile[rl * 512 + ((8 * l) ^ sw)]     = make_float4(a0, a1, a2, a3);
    *(float4*)&tile[rl * 512 + ((8 * l + 4) ^ sw)] = make_float4(a4, a5, a6, a7);
  }
  __syncthreads();
  int r = l & 31;
  int swr = (r & 7) << 2;
#pragma unroll
  for (int it = 0; it < 32; ++it) {
    int n = it * 16 + w * 2 + (l >> 5);
    out[(size_t)n * kC + r0 + r] = tile[r * 512 + (n ^ swr)];
  }
}

extern "C" void kernel_launch(void* const* d_in, const int* in_sizes, int n_in,
                              void* d_out, int out_size, void* d_ws, size_t ws_size,
                              hipStream_t stream) {
  (void)in_sizes; (void)n_in; (void)out_size; (void)ws_size;
  const float* enc   = (const float*)d_in[0];
  const float* W     = (const float*)d_in[1];
  const float* bias  = (const float*)d_in[2];
  const float* Avals = (const float*)d_in[3];
  const int*   bidx  = (const int*)d_in[4];
  const int*   tgt   = (const int*)d_in[5];
  const int*   Arow  = (const int*)d_in[6];
  const int*   Acol  = Arow + kNNZ;
  float* out = (float*)d_out;

  char* ws = (char*)d_ws;
  float* mean   = (float*)(ws);                       //   4 KB
  float* rstd   = (float*)(ws + 4096);                //   4 KB
  u16*   Bp     = (u16*)  (ws + 8192);                //   1 MB fragment-major h0
  int*   rowptr = (int*)  (ws + 1056768);             // 256 KB (+1)
  int*   cursor = (int*)  (ws + 1319168);             // 256 KB
  int*   scol   = (int*)  (ws + 1581312);             //   1 MB
  float* sval   = (float*)(ws + 2629888);             //   1 MB
  float* part   = (float*)(ws + 3678464);             //  64 KB
  u16*   h1t    = (u16*)  (ws + 4194304);             //  64 MB

  hipMemsetAsync(rowptr, 0, (kC + 1) * sizeof(int), stream);
  k_bn_part<<<dim3(4, 8), 256, 0, stream>>>(enc, bidx, tgt, part);
  k_bn_fin<<<4, 256, 0, stream>>>(part, mean, rstd);
  k_bn_pack<<<256, 256, 0, stream>>>(enc, bidx, tgt, mean, rstd, Bp);
  k_hist<<<kNNZ / 256, 256, 0, stream>>>(Arow, rowptr);
  k_scan<<<1, 1024, 0, stream>>>(rowptr, cursor);
  k_scatter<<<kNNZ / 256, 256, 0, stream>>>(Arow, Acol, Avals, cursor, scol, sval);
  k_gemm_f6<<<dim3(2, 1024), 256, 0, stream>>>(W, Bp, bias, h1t);
  k_spmm<<<kC / 32, 512, 0, stream>>>(h1t, rowptr, scol, sval, out);
}

// Round 12
// 293.113 us; speedup vs baseline: 1.2418x; 1.2418x over previous
//
#include <hip/hip_runtime.h>
#include <hip/hip_bf16.h>

typedef unsigned short u16;
typedef unsigned int   u32;
typedef __attribute__((ext_vector_type(8))) short bf16x8;
typedef __attribute__((ext_vector_type(4))) float f32x4;

static constexpr int kS = 128, kD = 1024, kC = 65536, kN = 512, kNNZ = 262144;

__device__ __forceinline__ u16 f2bf(float x) {
  u32 u = __float_as_uint(x);
  u32 r = (u + 0x7fffu + ((u >> 16) & 1u)) >> 16;   // RTNE
  return (u16)r;
}
__device__ __forceinline__ u32 pack2(float a, float b) {
  return (u32)f2bf(a) | ((u32)f2bf(b) << 16);
}
// HW packed convert: v_cvt_pk_bf16_f32 (RTNE), a -> low16, b -> high16
__device__ __forceinline__ u32 pk(float a, float b) {
  __hip_bfloat162 h = __float22bfloat162_rn(float2{a, b});
  union { __hip_bfloat162 v; u32 u; } c; c.v = h;
  return c.u;
}
__device__ __forceinline__ float bf_lo(u32 v) { return __uint_as_float(v << 16); }
__device__ __forceinline__ float bf_hi(u32 v) { return __uint_as_float(v & 0xffff0000u); }

__device__ __forceinline__ void gload16(const void* g, void* l) {
  __builtin_amdgcn_global_load_lds(
      (const __attribute__((address_space(1))) void*)g,
      (__attribute__((address_space(3))) void*)l, 16, 0, 0);
}

// ---------------- BN stats: two-stage partial sums ----------------
__global__ void k_bn_part(const float* __restrict__ enc, const int* __restrict__ bidx,
                          const int* __restrict__ tgt, float* __restrict__ part) {
  __shared__ int offs[64];
  int n0 = blockIdx.y * 64;
  if (threadIdx.x < 64) offs[threadIdx.x] = bidx[n0 + threadIdx.x] * kS + tgt[n0 + threadIdx.x];
  __syncthreads();
  int d = blockIdx.x * 256 + threadIdx.x;
  float s = 0.f, ss = 0.f;
  for (int i = 0; i < 64; ++i) {
    float v = enc[(size_t)offs[i] * kD + d];
    s += v; ss += v * v;
  }
  part[(blockIdx.y * 2 + 0) * kD + d] = s;
  part[(blockIdx.y * 2 + 1) * kD + d] = ss;
}

__global__ void k_bn_fin(const float* __restrict__ part, float* __restrict__ mean,
                         float* __restrict__ rstd) {
  int d = blockIdx.x * 256 + threadIdx.x;
  float s = 0.f, ss = 0.f;
#pragma unroll
  for (int b = 0; b < 8; ++b) {
    s  += part[(b * 2 + 0) * kD + d];
    ss += part[(b * 2 + 1) * kD + d];
  }
  float m = s * (1.f / kN);
  float var = ss * (1.f / kN) - m * m;
  mean[d] = m;
  rstd[d] = 1.f / sqrtf(var + 1e-5f);
}

// ---------------- BN apply + pack into fragment-major Bp ----------------
// Bp entry (g, n) at flat g*512+n, 8 bf16 = h0[n][g*8 .. g*8+8]
__global__ void k_bn_pack(const float* __restrict__ enc, const int* __restrict__ bidx,
                          const int* __restrict__ tgt, const float* __restrict__ mean,
                          const float* __restrict__ rstd, u16* __restrict__ Bp) {
  int i = blockIdx.x * 256 + threadIdx.x;     // 256 blocks x 256 = 65536 entries
  int n = i & 511;
  int g = i >> 9;
  int k0 = g * 8;
  size_t src = (size_t)(bidx[n] * kS + tgt[n]) * kD + k0;
  float4 v0 = *(const float4*)(enc + src);
  float4 v1 = *(const float4*)(enc + src + 4);
  float4 m0 = *(const float4*)(mean + k0);
  float4 m1 = *(const float4*)(mean + k0 + 4);
  float4 r0 = *(const float4*)(rstd + k0);
  float4 r1 = *(const float4*)(rstd + k0 + 4);
  u32 q0 = pack2((v0.x - m0.x) * r0.x, (v0.y - m0.y) * r0.y);
  u32 q1 = pack2((v0.z - m0.z) * r0.z, (v0.w - m0.w) * r0.w);
  u32 q2 = pack2((v1.x - m1.x) * r1.x, (v1.y - m1.y) * r1.y);
  u32 q3 = pack2((v1.z - m1.z) * r1.z, (v1.w - m1.w) * r1.w);
  *(uint4*)(Bp + (size_t)i * 8) = make_uint4(q0, q1, q2, q3);
}

// ---------------- sort: histogram / scan / scatter ----------------
__global__ void k_hist(const int* __restrict__ rows, int* __restrict__ hist) {
  int e = blockIdx.x * blockDim.x + threadIdx.x;
  if (e < kNNZ) atomicAdd(&hist[rows[e]], 1);
}

__global__ __launch_bounds__(1024) void k_scan(int* __restrict__ hist, int* __restrict__ cursor) {
  __shared__ int sm[1024];
  int t = threadIdx.x;
  int base = t * 64;
  int sum = 0;
  for (int i = 0; i < 64; ++i) sum += hist[base + i];
  sm[t] = sum;
  __syncthreads();
  for (int off = 1; off < 1024; off <<= 1) {
    int v = (t >= off) ? sm[t - off] : 0;
    __syncthreads();
    sm[t] += v;
    __syncthreads();
  }
  int run = sm[t] - sum;
  for (int i = 0; i < 64; ++i) {
    int v = hist[base + i];
    hist[base + i] = run;
    cursor[base + i] = run;
    run += v;
  }
  if (t == 1023) hist[kC] = run;
}

__global__ void k_scatter(const int* __restrict__ rows, const int* __restrict__ cols,
                          const float* __restrict__ vals, int* __restrict__ cursor,
                          int* __restrict__ scol, float* __restrict__ sval) {
  int e = blockIdx.x * blockDim.x + threadIdx.x;
  if (e < kNNZ) {
    int r = rows[e];
    int p = atomicAdd(&cursor[r], 1);
    scol[p] = cols[e];
    sval[p] = vals[e];
  }
}

// ---------------- fused GEMM v7: BM=128 x BN=512 (W once), BOTH operands LDS-staged ----------------
// 1024 thr (16 waves = 2m x 8n), BK=32, acc[4][4], 1 block/CU, grid 512 (2 rounds).
// B: fragment-major Bp -> 32 KB/phase contiguous -> global_load_lds DMA (linear src+dest,
//    no per-lane L1 traffic, no VALU). A: threads<512 reg-stage f32->cvt_pk->ds_write_b128
//    into [128][32] bf16 tile, slot^=(row&3) swizzle (write+read) -> conflict-free.
// One __syncthreads per phase; loads issued one phase ahead; dbuf both tiles (80 KB).
__global__ __launch_bounds__(1024, 4)
void k_gemm_f7(const float* __restrict__ W, const u16* __restrict__ Bp,
               const float* __restrict__ bias, u16* __restrict__ h1t) {
  __shared__ __align__(16) u16 Bb[2][16384];   // 2 x 32 KB: [4 g][512 n][8 bf16]
  __shared__ __align__(16) u16 Ab[2][4096];    // 2 x 8 KB:  [128 r][4 slots][8 bf16]
  const int t = threadIdx.x;
  const int l = t & 63, w = t >> 6;            // 16 waves
  const int wm = w >> 3, wn = (w & 7) * 64;    // 2 m-slots x 8 n-slots
  const int cb = blockIdx.x * 128;
  const int q = l >> 4, ln = l & 15;

  // B DMA: slots t and t+1024 of 2048; Bp phase stride = 2048*8 u16 = 32 KB
  const u16* gB0 = Bp + (size_t)t * 8;
  const u16* gB1 = Bp + (size_t)(t + 1024) * 8;

  // A staging (threads < 512): slot t -> row sr = t>>2, linear chunk c = t&3 (16B bf16 = 32B f32)
  const int sr = t >> 2;
  const float* gA = W + (size_t)(cb + sr) * kD + (t & 3) * 8;
  const int aws = sr * 32 + (((t & 3) ^ (sr & 3)) * 8);   // swizzled dest (u16 units)

  f32x4 acc[4][4];
#pragma unroll
  for (int a = 0; a < 4; ++a)
#pragma unroll
    for (int b = 0; b < 4; ++b) acc[a][b] = (f32x4){0.f, 0.f, 0.f, 0.f};

  // prologue: phase 0 into buffer 0
  gload16(gB0, (char*)Bb[0] + t * 16);
  gload16(gB1, (char*)Bb[0] + (t + 1024) * 16);
  if (t < 512) {
    float4 a0 = *(const float4*)(gA);
    float4 a1 = *(const float4*)(gA + 4);
    *(uint4*)(&Ab[0][aws]) =
        make_uint4(pk(a0.x, a0.y), pk(a0.z, a0.w), pk(a1.x, a1.y), pk(a1.z, a1.w));
  }
  __syncthreads();

#pragma unroll 2
  for (int tt = 0; tt < 32; ++tt) {
    const int cur = tt & 1;
    float4 na0, na1;
    if (tt < 31) {
      // issue next phase: B DMA + A global loads (in flight across this phase's MFMA)
      gload16(gB0 + (size_t)(tt + 1) * 16384, (char*)Bb[cur ^ 1] + t * 16);
      gload16(gB1 + (size_t)(tt + 1) * 16384, (char*)Bb[cur ^ 1] + (t + 1024) * 16);
      if (t < 512) {
        na0 = *(const float4*)(gA + (tt + 1) * 32);
        na1 = *(const float4*)(gA + (tt + 1) * 32 + 4);
      }
    }
    // compute phase tt
    bf16x8 bv[4], af[4];
#pragma unroll
    for (int nb = 0; nb < 4; ++nb)
      bv[nb] = *(const bf16x8*)(&Bb[cur][(q * 512 + wn + nb * 16 + ln) * 8]);
#pragma unroll
    for (int mb = 0; mb < 4; ++mb) {
      int rr = wm * 64 + mb * 16 + ln;
      af[mb] = *(const bf16x8*)(&Ab[cur][rr * 32 + ((q ^ (rr & 3)) * 8)]);
    }
#pragma unroll
    for (int mb = 0; mb < 4; ++mb)
#pragma unroll
      for (int nb = 0; nb < 4; ++nb)
        acc[mb][nb] = __builtin_amdgcn_mfma_f32_16x16x32_bf16(af[mb], bv[nb], acc[mb][nb], 0, 0, 0);
    // write next A tile (cvt waits on na loads; ~full phase of slack behind it)
    if (tt < 31 && t < 512) {
      *(uint4*)(&Ab[cur ^ 1][aws]) =
          make_uint4(pk(na0.x, na0.y), pk(na0.z, na0.w), pk(na1.x, na1.y), pk(na1.z, na1.w));
    }
    __syncthreads();
  }

  // epilogue: + bias, swish, bf16 store (C/D map: col=lane&15, row=(lane>>4)*4+i)
#pragma unroll
  for (int mb = 0; mb < 4; ++mb) {
    int rb = wm * 64 + mb * 16 + q * 4;
#pragma unroll
    for (int i = 0; i < 4; ++i) {
      int c = cb + rb + i;
      float bvs = bias[c];
#pragma unroll
      for (int nb = 0; nb < 4; ++nb) {
        float x = acc[mb][nb][i] + bvs;
        float sw = x / (1.f + __expf(-x));
        h1t[(size_t)c * kN + (wn + nb * 16 + ln)] = f2bf(sw);
      }
    }
  }
}

// ---------------- spmm: 32 rows/block, 2-deep edge pipeline, transposed write ----------------
#define FMA8(cv, v)                                                        \
  a0 = fmaf(v, bf_lo(cv.x), a0); a1 = fmaf(v, bf_hi(cv.x), a1);            \
  a2 = fmaf(v, bf_lo(cv.y), a2); a3 = fmaf(v, bf_hi(cv.y), a3);            \
  a4 = fmaf(v, bf_lo(cv.z), a4); a5 = fmaf(v, bf_hi(cv.z), a5);            \
  a6 = fmaf(v, bf_lo(cv.w), a6); a7 = fmaf(v, bf_hi(cv.w), a7);

__global__ __launch_bounds__(512)
void k_spmm(const u16* __restrict__ h1t, const int* __restrict__ rowptr,
            const int* __restrict__ scol, const float* __restrict__ sval,
            float* __restrict__ out) {
  __shared__ float tile[32 * 512];   // XOR-swizzled, 64 KB
  int r0 = blockIdx.x * 32;
  int t = threadIdx.x, w = t >> 6, l = t & 63;
#pragma unroll
  for (int j = 0; j < 4; ++j) {
    int rl = w * 4 + j;
    int r = r0 + rl;
    uint4 hv = ((const uint4*)(h1t + (size_t)r * kN))[l];
    float a0 = bf_lo(hv.x), a1 = bf_hi(hv.x), a2 = bf_lo(hv.y), a3 = bf_hi(hv.y);
    float a4 = bf_lo(hv.z), a5 = bf_hi(hv.z), a6 = bf_lo(hv.w), a7 = bf_hi(hv.w);
    int e0 = rowptr[r], e1 = rowptr[r + 1];
    uint4 cv0 = {}, cv1 = {};
    float v0 = 0.f, v1 = 0.f;
    if (e0 < e1) {                    // 2-deep pipeline: two independent gather regs
      v0 = sval[e0];
      cv0 = ((const uint4*)(h1t + (size_t)scol[e0] * kN))[l];
    }
    if (e0 + 1 < e1) {
      v1 = sval[e0 + 1];
      cv1 = ((const uint4*)(h1t + (size_t)scol[e0 + 1] * kN))[l];
    }
    for (int e = e0; e < e1; e += 2) {
      FMA8(cv0, v0);
      if (e + 2 < e1) {
        v0 = sval[e + 2];
        cv0 = ((const uint4*)(h1t + (size_t)scol[e + 2] * kN))[l];
      }
      if (e + 1 < e1) {
        FMA8(cv1, v1);
        if (e + 3 < e1) {
          v1 = sval[e + 3];
          cv1 = ((const uint4*)(h1t + (size_t)scol[e + 3] * kN))[l];
        }
      }
    }
    int sw = (rl & 7) << 2;          // XOR bits 2..4 keep float4 groups intact
    *(float4*)&tile[rl * 512 + ((8 * l) ^ sw)]     = make_float4(a0, a1, a2, a3);
    *(float4*)&tile[rl * 512 + ((8 * l + 4) ^ sw)] = make_float4(a4, a5, a6, a7);
  }
  __syncthreads();
  int r = l & 31;
  int swr = (r & 7) << 2;
#pragma unroll
  for (int it = 0; it < 32; ++it) {
    int n = it * 16 + w * 2 + (l >> 5);
    out[(size_t)n * kC + r0 + r] = tile[r * 512 + (n ^ swr)];
  }
}

extern "C" void kernel_launch(void* const* d_in, const int* in_sizes, int n_in,
                              void* d_out, int out_size, void* d_ws, size_t ws_size,
                              hipStream_t stream) {
  (void)in_sizes; (void)n_in; (void)out_size; (void)ws_size;
  const float* enc   = (const float*)d_in[0];
  const float* W     = (const float*)d_in[1];
  const float* bias  = (const float*)d_in[2];
  const float* Avals = (const float*)d_in[3];
  const int*   bidx  = (const int*)d_in[4];
  const int*   tgt   = (const int*)d_in[5];
  const int*   Arow  = (const int*)d_in[6];
  const int*   Acol  = Arow + kNNZ;
  float* out = (float*)d_out;

  char* ws = (char*)d_ws;
  float* mean   = (float*)(ws);                       //   4 KB
  float* rstd   = (float*)(ws + 4096);                //   4 KB
  u16*   Bp     = (u16*)  (ws + 8192);                //   1 MB fragment-major h0
  int*   rowptr = (int*)  (ws + 1056768);             // 256 KB (+1)
  int*   cursor = (int*)  (ws + 1319168);             // 256 KB
  int*   scol   = (int*)  (ws + 1581312);             //   1 MB
  float* sval   = (float*)(ws + 2629888);             //   1 MB
  float* part   = (float*)(ws + 3678464);             //  64 KB
  u16*   h1t    = (u16*)  (ws + 4194304);             //  64 MB

  hipMemsetAsync(rowptr, 0, (kC + 1) * sizeof(int), stream);
  k_bn_part<<<dim3(4, 8), 256, 0, stream>>>(enc, bidx, tgt, part);
  k_bn_fin<<<4, 256, 0, stream>>>(part, mean, rstd);
  k_bn_pack<<<256, 256, 0, stream>>>(enc, bidx, tgt, mean, rstd, Bp);
  k_hist<<<kNNZ / 256, 256, 0, stream>>>(Arow, rowptr);
  k_scan<<<1, 1024, 0, stream>>>(rowptr, cursor);
  k_scatter<<<kNNZ / 256, 256, 0, stream>>>(Arow, Acol, Avals, cursor, scol, sval);
  k_gemm_f7<<<512, 1024, 0, stream>>>(W, Bp, bias, h1t);
  k_spmm<<<kC / 32, 512, 0, stream>>>(h1t, rowptr, scol, sval, out);
}